// Round 3
// baseline (601.430 us; speedup 1.0000x reference)
//
#include <hip/hip_runtime.h>
#include <hip/hip_bf16.h>

// LSAPPNP: h = relu(x@W1+b1); h2 = h@W2+b2; agg[r] += val*h2[c] over edges;
// out = log_softmax(0.1*h2 + agg, axis=1)
// N=100000, F_IN=500, HID=256, C=40, E~2.3M
//
// Round 9: barrier-free MLP. Three schedule variants all plateaued at
// ~130us -> the per-K-iter block-wide barrier convoy is the bottleneck,
// not the schedule. New geometry: each wave owns 16 rows x 256 cols
// (acc 64 VGPR), A-frags straight from x to registers (no LDS staging),
// B from L2-hot W1S. Wave holds full h[16][256] in acc, so GEMM2 needs
// only an intra-wave 8KB LDS transpose. ZERO barriers in the kernel;
// waves free-run, latency hidden by 16 indep waves/CU.

#define N_NODES 100000
#define F_IN    500
#define HID     256
#define C_OUT   40
#define ALPHA0  0.1f
#define H2STRIDE 64

#define RPB     128                           // rows per bucket
#define NBUCK   ((N_NODES + RPB - 1) / RPB)   // 782
#define NCH     320                           // edge chunks (hist/split blocks)
#define SCAN_M  (NBUCK * NCH)                 // 250240
#define SCAN_CHUNK 2048
#define NBS     ((SCAN_M + SCAN_CHUNK - 1) / SCAN_CHUNK)  // 123

typedef short short8 __attribute__((ext_vector_type(8)));
typedef float f32x4  __attribute__((ext_vector_type(4)));

__device__ __forceinline__ short f2bf(float f) {
  union { float f; unsigned u; } x; x.f = f;
  unsigned r = x.u + 0x7fffu + ((x.u >> 16) & 1u);  // RNE
  return (short)(r >> 16);
}
__device__ __forceinline__ float bf2f(short s) {
  union { unsigned u; float f; } x; x.u = ((unsigned)(unsigned short)s) << 16;
  return x.f;
}
// packed f32x2 -> bf16x2 (RNE), single VOP3
__device__ __forceinline__ unsigned cvtpk(float lo, float hi) {
  unsigned r;
  asm("v_cvt_pk_bf16_f32 %0, %1, %2" : "=v"(r) : "v"(lo), "v"(hi));
  return r;
}

// ---- K0: pack W1 -> W1S [16 kchunks][256 n][32 k] bf16; W2 -> W2T [48 n][256 k]
__global__ __launch_bounds__(256) void k_pack_weights(
    const float* __restrict__ W1, const float* __restrict__ W2,
    short* __restrict__ W1S, short* __restrict__ W2T)
{
  int i = blockIdx.x * 256 + threadIdx.x;
  if (i < 16*256*32) {
    int kc  = i >> 13;
    int idx = i & 8191;
    int n   = idx >> 5;
    int kk  = idx & 31;
    int k   = kc*32 + kk;
    float v = (k < F_IN) ? W1[k*HID + n] : 0.f;
    W1S[i] = f2bf(v);
  } else {
    int j = i - 16*256*32;
    if (j < 48*256) {
      int n = j >> 8;
      int k = j & 255;
      float v = (n < C_OUT) ? W2[k*C_OUT + n] : 0.f;
      W2T[j] = f2bf(v);
    }
  }
}

// ---- K1: barrier-free fused MLP. 256 thr = 4 waves; each wave: 16 rows.
// A-frag: lane(lr,quad) reads x[row0+w*16+lr][kc*32+quad*8 ..+7] (regs).
// GEMM1: 16 col-tiles, acc[16] = h[16][256] per wave.
// GEMM2: per-wave 8KB LDS transpose (XOR-swizzled), W2T from L1/L2.
__global__ __launch_bounds__(256, 4) void k_fused_mlp(
    const float* __restrict__ x, const float* __restrict__ b1v,
    const float* __restrict__ b2v,
    const short* __restrict__ W1S, const short* __restrict__ W2T,
    short* __restrict__ h2b)
{
  __shared__ __align__(16) char smem[32768];   // 4 waves x 8KB scratch

  const int tid  = threadIdx.x;
  const int w    = tid >> 6;
  const int lane = tid & 63;
  const int lr   = lane & 15;
  const int quad = lane >> 4;
  const int row0 = blockIdx.x * 64;

  const int myrow = row0 + w*16 + lr;
  const float* ap = x + (size_t)min(myrow, N_NODES - 1) * F_IN;

  f32x4 acc[16] = {};   // [ct]: D[row=quad*4+r][col=ct*16+lr]

  // preload kc=0 A-slice (k = quad*8 .. +7, all < 32 <= 500)
  float cur[8];
  {
    int kb = quad * 8;
    f32x4 u0 = *(const f32x4*)(ap + kb);
    f32x4 u1 = *(const f32x4*)(ap + kb + 4);
    #pragma unroll
    for (int j = 0; j < 4; ++j) { cur[j] = u0[j]; cur[4+j] = u1[j]; }
  }

  const short* bb0 = W1S + lr*32 + quad*8;

  for (int kc = 0; kc < 16; ++kc) {
    // prefetch next A-slice into regs (stays in flight across the MFMAs)
    float nxt[8];
    if (kc < 15) {
      int kb = (kc + 1)*32 + quad*8;
      if (kb + 8 <= F_IN) {
        f32x4 u0 = *(const f32x4*)(ap + kb);
        f32x4 u1 = *(const f32x4*)(ap + kb + 4);
        #pragma unroll
        for (int j = 0; j < 4; ++j) { nxt[j] = u0[j]; nxt[4+j] = u1[j]; }
      } else {
        #pragma unroll
        for (int j = 0; j < 8; ++j)
          nxt[j] = (kb + j < F_IN) ? ap[kb + j] : 0.f;
      }
    }

    // current A-frag -> bf16
    short8 af;
    {
      union { unsigned u[4]; short8 s; } pk;
      pk.u[0] = cvtpk(cur[0], cur[1]);
      pk.u[1] = cvtpk(cur[2], cur[3]);
      pk.u[2] = cvtpk(cur[4], cur[5]);
      pk.u[3] = cvtpk(cur[6], cur[7]);
      af = pk.s;
    }

    // 16 col-tiles: grouped 4 loads + 4 MFMAs (compiler pipelines groups)
    const short* bb = bb0 + kc*8192;
    #pragma unroll
    for (int g = 0; g < 4; ++g) {
      short8 bq[4];
      #pragma unroll
      for (int t = 0; t < 4; ++t)
        bq[t] = *(const short8*)(bb + (g*4 + t)*16*32);
      #pragma unroll
      for (int t = 0; t < 4; ++t)
        acc[g*4 + t] = __builtin_amdgcn_mfma_f32_16x16x32_bf16(af, bq[t], acc[g*4 + t], 0, 0, 0);
    }

    if (kc < 15) {
      #pragma unroll
      for (int j = 0; j < 8; ++j) cur[j] = nxt[j];
    }
  }

  // epilogue 1: relu(acc + b1) -> per-wave LDS scratch (XOR-swizzled 16B slots)
  short (*Hw)[256] = (short(*)[256])(smem + w*8192);
  #pragma unroll
  for (int ct = 0; ct < 16; ++ct) {
    int col = ct*16 + lr;
    int cg = col >> 3, ci = col & 7;
    float bias = b1v[col];
    #pragma unroll
    for (int r = 0; r < 4; ++r) {
      int row = quad*4 + r;
      float v = fmaxf(acc[ct][r] + bias, 0.f);
      Hw[row][((cg ^ row) << 3) | ci] = f2bf(v);
    }
  }
  // intra-wave ds_write -> ds_read ordering: compiler-inserted lgkmcnt; no barrier.

  // GEMM2: this wave's 16 rows x 48 padded cols, K=256
  f32x4 acc2[3] = {};
  const int arow = lr;
  #pragma unroll
  for (int kc2 = 0; kc2 < 8; ++kc2) {
    int gg = kc2*4 + quad;
    short8 a2 = *(const short8*)&Hw[arow][(gg ^ arow) << 3];
    #pragma unroll
    for (int nt = 0; nt < 3; ++nt) {
      short8 b2 = *(const short8*)(W2T + (nt*16 + lr)*256 + kc2*32 + quad*8);
      acc2[nt] = __builtin_amdgcn_mfma_f32_16x16x32_bf16(a2, b2, acc2[nt], 0, 0, 0);
    }
  }

  // epilogue 2: h2b = bf16(acc2 + b2), stride 64, cols >= C_OUT zeroed
  #pragma unroll
  for (int nt = 0; nt < 3; ++nt) {
    int col = nt*16 + lr;
    float bias = (col < C_OUT) ? b2v[col] : 0.f;
    #pragma unroll
    for (int r = 0; r < 4; ++r) {
      int row = row0 + w*16 + quad*4 + r;
      if (row < N_NODES) {
        float v = (col < C_OUT) ? (acc2[nt][r] + bias) : 0.f;
        h2b[(long)row * H2STRIDE + col] = f2bf(v);
      }
    }
  }
  {
    int col = 48 + lr;
    #pragma unroll
    for (int r = 0; r < 4; ++r) {
      int row = row0 + w*16 + quad*4 + r;
      if (row < N_NODES) h2b[(long)row * H2STRIDE + col] = 0;
    }
  }
}

// ---- K2: per-chunk LDS histogram of buckets (row>>7). offs[b*NCH + c] = count
__global__ __launch_bounds__(256) void k_hist2(
    const int* __restrict__ erow, int* __restrict__ offs, int E, int CH)
{
  __shared__ int h[NBUCK];
  int tid = threadIdx.x, c = blockIdx.x;
  for (int b = tid; b < NBUCK; b += 256) h[b] = 0;
  __syncthreads();
  int e0 = c * CH, e1 = min(E, e0 + CH);
  for (int e = e0 + tid; e < e1; e += 256)
    atomicAdd(&h[erow[e] >> 7], 1);
  __syncthreads();
  for (int b = tid; b < NBUCK; b += 256) offs[b * NCH + c] = h[b];
}

// ---- K3a: scan phase 1 — 2048-elem chunks, in-place exclusive scan + sums
__global__ __launch_bounds__(256) void k_scan1(
    int* __restrict__ offs, int* __restrict__ bsums)
{
  __shared__ int sh[256];
  int tid = threadIdx.x;
  int base = blockIdx.x * SCAN_CHUNK + tid * 8;
  int d[8];
  #pragma unroll
  for (int k = 0; k < 8; ++k)
    d[k] = (base + k < SCAN_M) ? offs[base + k] : 0;
  int s = 0;
  #pragma unroll
  for (int k = 0; k < 8; ++k) s += d[k];
  sh[tid] = s;
  __syncthreads();
  for (int o = 1; o < 256; o <<= 1) {
    int v = (tid >= o) ? sh[tid - o] : 0;
    __syncthreads();
    if (tid >= o) sh[tid] += v;
    __syncthreads();
  }
  int run = sh[tid] - s;
  #pragma unroll
  for (int k = 0; k < 8; ++k) {
    if (base + k < SCAN_M) offs[base + k] = run;
    run += d[k];
  }
  if (tid == 255) bsums[blockIdx.x] = sh[255];
}

// ---- K3b: scan phase 2 — exclusive scan of NBS block sums (single block)
__global__ __launch_bounds__(256) void k_scan2(int* __restrict__ bsums) {
  __shared__ int sh[256];
  int tid = threadIdx.x;
  int v = (tid < NBS) ? bsums[tid] : 0;
  sh[tid] = v;
  __syncthreads();
  for (int o = 1; o < 256; o <<= 1) {
    int u = (tid >= o) ? sh[tid - o] : 0;
    __syncthreads();
    if (tid >= o) sh[tid] += u;
    __syncthreads();
  }
  if (tid < NBS) bsums[tid] = sh[tid] - v;
}

// ---- K3c: scan phase 3 — add block offsets
__global__ __launch_bounds__(256) void k_scan3(
    int* __restrict__ offs, const int* __restrict__ bsums)
{
  int i = blockIdx.x * 256 + threadIdx.x;
  if (i < SCAN_M) offs[i] += bsums[i >> 11];
}

// ---- K4: split edges into bucket-grouped order (LDS cursors, no dev atomics).
// sorted[pos] = { col | rowlow<<17 , val }
__global__ __launch_bounds__(256) void k_split(
    const int* __restrict__ erow, const int* __restrict__ ecol,
    const float* __restrict__ eval, const int* __restrict__ offs,
    int2* __restrict__ sorted, int E, int CH)
{
  __shared__ int cur[NBUCK];
  int tid = threadIdx.x, c = blockIdx.x;
  for (int b = tid; b < NBUCK; b += 256) cur[b] = offs[b * NCH + c];
  __syncthreads();
  int e0 = c * CH, e1 = min(E, e0 + CH);
  for (int e = e0 + tid; e < e1; e += 256) {
    int r = erow[e];
    int b = r >> 7;
    int pos = atomicAdd(&cur[b], 1);
    int2 cv;
    cv.x = ecol[e] | ((r & 127) << 17);
    cv.y = __float_as_int(eval[e]);
    sorted[pos] = cv;
  }
}

// ---- K5: per-bucket CSR finalize -> sorted2 (row-ordered) + row_offs[N+1]
__global__ __launch_bounds__(256) void k_csr(
    const int* __restrict__ offs, const int2* __restrict__ sorted,
    int2* __restrict__ sorted2, int* __restrict__ row_offs, int E)
{
  __shared__ int hist[RPB];
  __shared__ int scn[RPB];
  int tid = threadIdx.x, b = blockIdx.x;
  int start = offs[b * NCH];
  int end   = (b + 1 < NBUCK) ? offs[(b + 1) * NCH] : E;

  if (tid < RPB) hist[tid] = 0;
  __syncthreads();
  for (int e = start + tid; e < end; e += 256)
    atomicAdd(&hist[((unsigned)sorted[e].x) >> 17], 1);
  __syncthreads();
  if (tid < RPB) scn[tid] = hist[tid];
  __syncthreads();
  for (int o = 1; o < RPB; o <<= 1) {
    int v = (tid >= o && tid < RPB) ? scn[tid - o] : 0;
    __syncthreads();
    if (tid >= o && tid < RPB) scn[tid] += v;
    __syncthreads();
  }
  if (tid < RPB) {
    int excl = scn[tid] - hist[tid];
    int row = b * RPB + tid;
    if (row < N_NODES) row_offs[row] = start + excl;
    hist[tid] = excl;   // reuse as in-bucket cursor
  }
  __syncthreads();
  for (int e = start + tid; e < end; e += 256) {
    int2 cv = sorted[e];
    int rl = ((unsigned)cv.x) >> 17;
    int pos = start + atomicAdd(&hist[rl], 1);
    sorted2[pos] = cv;
  }
  if (b == 0 && tid == 0) row_offs[N_NODES] = E;
}

// ---- K6: wave-per-row gather SpMM + fused log_softmax (4 rows/block).
// h2b stride 64: each gather is one aligned 128B line, all 64 lanes active.
__global__ __launch_bounds__(256) void k_spmm_lsm(
    const int* __restrict__ row_offs, const int2* __restrict__ sorted2,
    const short* __restrict__ h2b, float* __restrict__ out)
{
  int row  = blockIdx.x * 4 + (threadIdx.x >> 6);
  int lane = threadIdx.x & 63;
  if (row >= N_NODES) return;

  float acc = ALPHA0 * bf2f(h2b[(long)row * H2STRIDE + lane]);  // 0 for lane>=40

  int e   = row_offs[row];
  int end = row_offs[row + 1];
  for (; e + 3 < end; e += 4) {
    int2 cv0 = sorted2[e];
    int2 cv1 = sorted2[e + 1];
    int2 cv2 = sorted2[e + 2];
    int2 cv3 = sorted2[e + 3];
    int c0 = cv0.x & 0x1FFFF, c1 = cv1.x & 0x1FFFF;
    int c2 = cv2.x & 0x1FFFF, c3 = cv3.x & 0x1FFFF;
    float g0 = bf2f(h2b[(long)c0 * H2STRIDE + lane]);
    float g1 = bf2f(h2b[(long)c1 * H2STRIDE + lane]);
    float g2 = bf2f(h2b[(long)c2 * H2STRIDE + lane]);
    float g3 = bf2f(h2b[(long)c3 * H2STRIDE + lane]);
    acc += __int_as_float(cv0.y) * g0;
    acc += __int_as_float(cv1.y) * g1;
    acc += __int_as_float(cv2.y) * g2;
    acc += __int_as_float(cv3.y) * g3;
  }
  for (; e < end; ++e) {
    int2 cv = sorted2[e];
    int c0 = cv.x & 0x1FFFF;
    acc += __int_as_float(cv.y) * bf2f(h2b[(long)c0 * H2STRIDE + lane]);
  }

  float m = (lane < C_OUT) ? acc : -INFINITY;
  #pragma unroll
  for (int o = 32; o > 0; o >>= 1) m = fmaxf(m, __shfl_xor(m, o));
  float ev = (lane < C_OUT) ? __expf(acc - m) : 0.f;
  float s = ev;
  #pragma unroll
  for (int o = 32; o > 0; o >>= 1) s += __shfl_xor(s, o);
  if (lane < C_OUT) out[(long)row * C_OUT + lane] = acc - m - __logf(s);
}

extern "C" void kernel_launch(void* const* d_in, const int* in_sizes, int n_in,
                              void* d_out, int out_size, void* d_ws, size_t ws_size,
                              hipStream_t stream) {
  const float* x    = (const float*)d_in[0];
  const float* W1   = (const float*)d_in[1];
  const float* b1   = (const float*)d_in[2];
  const float* W2   = (const float*)d_in[3];
  const float* b2   = (const float*)d_in[4];
  const int*   erow = (const int*)d_in[5];
  const int*   ecol = (const int*)d_in[6];
  const float* eval = (const float*)d_in[7];
  const int E  = in_sizes[5];
  const int CH = (E + NCH - 1) / NCH;

  // ws: h2b 12.8MB | W1S 256KB | W2T 24KB | offs ~1MB | bsums 1KB |
  //     row_offs 400KB | sorted E*8B | sorted2 E*8B   (~52 MB)
  char* p = (char*)d_ws;
  short* h2b      = (short*)p;  p += (size_t)N_NODES * H2STRIDE * 2;
  short* W1S      = (short*)p;  p += (size_t)16*256*32 * 2;
  short* W2T      = (short*)p;  p += (size_t)48*256 * 2;
  int*   offs     = (int*)p;    p += (size_t)SCAN_M * 4;
  int*   bsums    = (int*)p;    p += 256 * 4;
  int*   row_offs = (int*)p;    p += (size_t)(N_NODES + 4) * 4;
  int2*  sorted   = (int2*)p;   p += (size_t)E * 8;
  int2*  sorted2  = (int2*)p;
  float* out = (float*)d_out;

  k_pack_weights<<<(16*256*32 + 48*256 + 255)/256, 256, 0, stream>>>(W1, W2, W1S, W2T);
  k_fused_mlp<<<(N_NODES + 63)/64, 256, 0, stream>>>(x, b1, b2, W1S, W2T, h2b);
  k_hist2<<<NCH, 256, 0, stream>>>(erow, offs, E, CH);
  k_scan1<<<NBS, 256, 0, stream>>>(offs, bsums);
  k_scan2<<<1, 256, 0, stream>>>(bsums);
  k_scan3<<<(SCAN_M + 255)/256, 256, 0, stream>>>(offs, bsums);
  k_split<<<NCH, 256, 0, stream>>>(erow, ecol, eval, offs, sorted, E, CH);
  k_csr<<<NBUCK, 256, 0, stream>>>(offs, sorted, sorted2, row_offs, E);
  k_spmm_lsm<<<(N_NODES + 3)/4, 256, 0, stream>>>(row_offs, sorted2, h2b, out);
}